// Round 8
// baseline (905.587 us; speedup 1.0000x reference)
//
#include <hip/hip_runtime.h>

#define E_TOT 160000
#define TPB   128
#define NTILE 1250       // 1250*128 == 160000 exactly
#define NBLK  (NTILE*4)  // one block per (edge-tile, pair)
#define ARENA 49         // f32 words/thread: ef[0..16] | h[17..48] (h1 then h2)

struct P4 { const float *w1, *b1, *w2, *b2, *w3, *b3; };

__global__ __launch_bounds__(TPB, 3) void edge_phase_kernel(
    const float* __restrict__ feat0, const float* __restrict__ feat1,
    const float* __restrict__ wE,    const float* __restrict__ radial,
    const float* __restrict__ b00,   const float* __restrict__ b01,
    const float* __restrict__ b10,   const float* __restrict__ b11,
    const int* __restrict__ src_idx,
    P4 W0, P4 W1, P4 W2, P4 W3,
    float* __restrict__ out)
{
  __shared__ float lds[TPB * ARENA];               // 25,088 B -> 6 blocks/CU (12 waves)
  const int tid  = threadIdx.x;
  const int p    = blockIdx.x & 3;                 // pair id (wave-uniform)
  const int tile = blockIdx.x >> 2;
  const int e    = tile * TPB + tid;
  float* A = lds + tid * ARENA;                    // stride 49 (odd): 2-way aliasing = free

  const float* __restrict__ w1 = (p==0)?W0.w1:(p==1)?W1.w1:(p==2)?W2.w1:W3.w1;
  const float* __restrict__ b1 = (p==0)?W0.b1:(p==1)?W1.b1:(p==2)?W2.b1:W3.b1;
  const float* __restrict__ w2 = (p==0)?W0.w2:(p==1)?W1.w2:(p==2)?W2.w2:W3.w2;
  const float* __restrict__ b2 = (p==0)?W0.b2:(p==1)?W1.b2:(p==2)?W2.b2:W3.b2;
  const float* __restrict__ w3 = (p==0)?W0.w3:(p==1)?W1.w3:(p==2)?W2.w3:W3.w3;
  const float* __restrict__ b3 = (p==0)?W0.b3:(p==1)?W1.b3:(p==2)?W2.b3:W3.b3;

  // ---- stage edge features into LDS: ef[0..15]=w row, ef[16]=radial ----
  {
    const float4* wp = (const float4*)(wE + (size_t)e * 16);
    float4 a = wp[0], b = wp[1], c = wp[2], d = wp[3];
    A[0]=a.x;  A[1]=a.y;  A[2]=a.z;  A[3]=a.w;
    A[4]=b.x;  A[5]=b.y;  A[6]=b.z;  A[7]=b.w;
    A[8]=c.x;  A[9]=c.y;  A[10]=c.z; A[11]=c.w;
    A[12]=d.x; A[13]=d.y; A[14]=d.z; A[15]=d.w;
    A[16] = radial[e];
  }
  const int idx = src_idx[e];

  // ---------- radial MLP (shared by all phases): ef -> h2 in A[17..48] ----------
  {
    float h[32];
    #pragma unroll
    for (int m = 0; m < 32; ++m) h[m] = b1[m];
    #pragma unroll 1
    for (int c = 0; c < 2; ++c){                   // k-chunks of 8
      float x[8];
      #pragma unroll
      for (int j = 0; j < 8; ++j) x[j] = A[c*8 + j];
      const float* __restrict__ r = w1 + c * 256;
      #pragma unroll
      for (int j = 0; j < 8; ++j){
        #pragma unroll
        for (int m = 0; m < 32; ++m) h[m] = fmaf(x[j], r[j*32 + m], h[m]);
      }
    }
    {                                              // k = 16 tail (radial)
      float x = A[16];
      const float* __restrict__ r = w1 + 512;
      #pragma unroll
      for (int m = 0; m < 32; ++m) h[m] = fmaf(x, r[m], h[m]);
    }
    #pragma unroll
    for (int m = 0; m < 32; ++m) A[17 + m] = fmaxf(h[m], 0.f);
    float g[32];
    #pragma unroll
    for (int m = 0; m < 32; ++m) g[m] = b2[m];
    #pragma unroll 1
    for (int c = 0; c < 4; ++c){                   // k-chunks of 8
      float x[8];
      #pragma unroll
      for (int j = 0; j < 8; ++j) x[j] = A[17 + c*8 + j];
      const float* __restrict__ r = w2 + c * 256;
      #pragma unroll
      for (int j = 0; j < 8; ++j){
        #pragma unroll
        for (int m = 0; m < 32; ++m) g[m] = fmaf(x[j], r[j*32 + m], g[m]);
      }
    }
    #pragma unroll
    for (int m = 0; m < 32; ++m) A[17 + m] = fmaxf(g[m], 0.f);   // h2 replaces h1
  }

  if (p < 3){
    // ---- source vector for this phase ----
    float v[8];
    if (p == 2){
      float B10[3];
      #pragma unroll
      for (int q = 0; q < 3; ++q) B10[q] = b10[(size_t)e*3 + q];
      const float4* f1 = (const float4*)(feat1 + (size_t)idx * 24);
      float s1[24];
      #pragma unroll
      for (int j = 0; j < 6; ++j){
        float4 t = f1[j];
        s1[4*j+0]=t.x; s1[4*j+1]=t.y; s1[4*j+2]=t.z; s1[4*j+3]=t.w;
      }
      #pragma unroll
      for (int i = 0; i < 8; ++i)
        v[i] = fmaf(B10[0], s1[3*i+0], fmaf(B10[1], s1[3*i+1], B10[2]*s1[3*i+2]));
    } else {
      const float4* f0 = (const float4*)(feat0 + (size_t)idx * 8);
      float4 a = f0[0], b = f0[1];
      v[0]=a.x; v[1]=a.y; v[2]=a.z; v[3]=a.w;
      v[4]=b.x; v[5]=b.y; v[6]=b.z; v[7]=b.w;
    }
    // ---- layer-3 matvec, 64 cols ----
    float acc[8];
    #pragma unroll
    for (int o = 0; o < 8; ++o){
      float t = 0.f;
      #pragma unroll
      for (int i = 0; i < 8; ++i) t = fmaf(b3[o*8 + i], v[i], t);
      acc[o] = t;
    }
    #pragma unroll 1
    for (int c = 0; c < 4; ++c){                   // m-chunks of 8
      float hh[8];
      #pragma unroll
      for (int j = 0; j < 8; ++j) hh[j] = A[17 + c*8 + j];
      const float* __restrict__ rb = w3 + c * 512;
      #pragma unroll
      for (int j = 0; j < 8; ++j){
        const float* __restrict__ r = rb + j * 64;
        #pragma unroll
        for (int o = 0; o < 8; ++o){
          float t = 0.f;
          #pragma unroll
          for (int i = 0; i < 8; ++i) t = fmaf(r[o*8 + i], v[i], t);
          acc[o] = fmaf(hh[j], t, acc[o]);
        }
      }
    }
    // ---- accumulate into out ----
    if (p == 0){
      const float bB = b00[e];
      float* o0 = out + (size_t)e * 8;
      #pragma unroll
      for (int o = 0; o < 8; ++o) atomicAdd(o0 + o, acc[o] * bB);
    } else if (p == 2){
      float* o0 = out + (size_t)e * 8;
      #pragma unroll
      for (int o = 0; o < 8; ++o) atomicAdd(o0 + o, acc[o]);
    } else {                                       // p == 1: rank-1 into out1
      float B01[3];
      #pragma unroll
      for (int q = 0; q < 3; ++q) B01[q] = b01[(size_t)e*3 + q];
      float* o1 = out + (size_t)E_TOT * 8 + (size_t)e * 24;
      #pragma unroll
      for (int o = 0; o < 8; ++o){
        #pragma unroll
        for (int q = 0; q < 3; ++q)
          atomicAdd(o1 + o*3 + q, acc[o] * B01[q]);
      }
    }
  } else {
    // ---------- pair (1,1): per-o R-slice + D-contraction ----------
    float s1[24];
    {
      const float4* f1 = (const float4*)(feat1 + (size_t)idx * 24);
      #pragma unroll
      for (int j = 0; j < 6; ++j){
        float4 t = f1[j];
        s1[4*j+0]=t.x; s1[4*j+1]=t.y; s1[4*j+2]=t.z; s1[4*j+3]=t.w;
      }
    }
    float Bv[27];
    const float* __restrict__ bp = b11 + (size_t)e * 27;   // [p][q][f]
    #pragma unroll
    for (int j = 0; j < 27; ++j) Bv[j] = bp[j];
    float* o1 = out + (size_t)E_TOT * 8 + (size_t)e * 24;
    #pragma unroll 1
    for (int o = 0; o < 8; ++o){
      float a24[24];                                // R[o,i,f] = a24[i*3+f]
      const float* __restrict__ b3o = b3 + o * 24;
      #pragma unroll
      for (int j = 0; j < 24; ++j) a24[j] = b3o[j];
      #pragma unroll 1
      for (int c = 0; c < 4; ++c){                  // m-chunks of 8
        float hh[8];
        #pragma unroll
        for (int j = 0; j < 8; ++j) hh[j] = A[17 + c*8 + j];
        const float* __restrict__ rb = w3 + c * 1536 + o * 24;
        #pragma unroll
        for (int jj = 0; jj < 8; ++jj){
          const float* __restrict__ r = rb + jj * 192;      // 24-contig segment
          #pragma unroll
          for (int j = 0; j < 24; ++j) a24[j] = fmaf(hh[jj], r[j], a24[j]);
        }
      }
      // D[q,f] = sum_i R[o,i,f] * s1[i,q]
      float D[9];
      #pragma unroll
      for (int q = 0; q < 3; ++q){
        #pragma unroll
        for (int f = 0; f < 3; ++f){
          float t = 0.f;
          #pragma unroll
          for (int i = 0; i < 8; ++i) t = fmaf(a24[i*3 + f], s1[i*3 + q], t);
          D[q*3 + f] = t;
        }
      }
      #pragma unroll
      for (int pp = 0; pp < 3; ++pp){
        float t = 0.f;
        #pragma unroll
        for (int q = 0; q < 3; ++q){
          #pragma unroll
          for (int f = 0; f < 3; ++f)
            t = fmaf(Bv[pp*9 + q*3 + f], D[q*3 + f], t);
        }
        atomicAdd(o1 + o*3 + pp, t);
      }
    }
  }
}

extern "C" void kernel_launch(void* const* d_in, const int* in_sizes, int n_in,
                              void* d_out, int out_size, void* d_ws, size_t ws_size,
                              hipStream_t stream)
{
  const float* feat0 = (const float*)d_in[0];
  const float* feat1 = (const float*)d_in[1];
  const float* wE    = (const float*)d_in[2];
  const float* rad   = (const float*)d_in[3];
  const float* b00   = (const float*)d_in[4];
  const float* b01   = (const float*)d_in[11];
  const float* b10   = (const float*)d_in[18];
  const float* b11   = (const float*)d_in[25];
  const int* sidx    = (const int*)d_in[32];

  P4 W[4];
  for (int p = 0; p < 4; ++p){
    W[p].w1 = (const float*)d_in[5  + 7*p];
    W[p].b1 = (const float*)d_in[6  + 7*p];
    W[p].w2 = (const float*)d_in[7  + 7*p];
    W[p].b2 = (const float*)d_in[8  + 7*p];
    W[p].w3 = (const float*)d_in[9  + 7*p];
    W[p].b3 = (const float*)d_in[10 + 7*p];
  }

  // zero the accumulation target (out is re-poisoned before every launch)
  hipMemsetAsync(d_out, 0, (size_t)out_size * sizeof(float), stream);

  edge_phase_kernel<<<NBLK, TPB, 0, stream>>>(feat0, feat1, wE, rad,
                                              b00, b01, b10, b11,
                                              sidx, W[0], W[1], W[2], W[3],
                                              (float*)d_out);
}

// Round 10
// 264.092 us; speedup vs baseline: 3.4291x; 3.4291x over previous
//
#include <hip/hip_runtime.h>

typedef unsigned int u32;
typedef unsigned short u16;
typedef _Float16 v2h __attribute__((ext_vector_type(2)));
typedef __fp16   v2fp __attribute__((ext_vector_type(2)));

#define E_TOT 160000
#define TPB   256
#define NBLK  1250        // (E/256)=625 tiles x 2 classes
#define ARENA 27          // u32/thread: xp[0..8] | hp[9..25] (17) | pad
// ws (u32, f16-pairs): [p(0,0):0..1920) [p(1,0):1920..3840) [p(0,1):3840..5760) [p(1,1):5760..9856)
// per p<3 pair: W1p[9][32]@+0 | W2p[17][32]@+288 | W3p[34 rows][32 cp]@+832   (rows 32=b3,33=0)
// p3 pair:      W1p@+0 | W2p@+288 | W3p[17 mp][192 c]@+832                     (mp16=(b3,0))

#if __has_builtin(__builtin_amdgcn_fdot2)
__device__ __forceinline__ float FDOT2(v2h a, v2h b, float c){
  return __builtin_amdgcn_fdot2(a, b, c, false);
}
#else
__device__ __forceinline__ float FDOT2(v2h a, v2h b, float c){
  return fmaf((float)a[0], (float)b[0], fmaf((float)a[1], (float)b[1], c));
}
#endif

__device__ __forceinline__ u32 pkh(float a, float b){
  union { v2fp h; u32 x; } u;
  u.h = __builtin_amdgcn_cvt_pkrtz(a, b);
  return u.x;
}
__device__ __forceinline__ v2h asvh(u32 x){
  union { u32 x; v2h h; } u; u.x = x; return u.h;
}

struct WPtrs { const float* p[24]; };  // pair order (0,0),(1,0),(0,1),(1,1) x {w1,b1,w2,b2,w3,b3}

__global__ __launch_bounds__(256) void prep_kernel(WPtrs S, u32* __restrict__ ws)
{
  const int t = blockIdx.x * 256 + threadIdx.x;
  if (t >= 9856) return;
  int pair, rel;
  if (t < 5760){ pair = t / 1920; rel = t % 1920; }
  else         { pair = 3;        rel = t - 5760; }
  const float* __restrict__ w1 = S.p[pair*6+0];
  const float* __restrict__ b1 = S.p[pair*6+1];
  const float* __restrict__ w2 = S.p[pair*6+2];
  const float* __restrict__ b2 = S.p[pair*6+3];
  const float* __restrict__ w3 = S.p[pair*6+4];
  const float* __restrict__ b3 = S.p[pair*6+5];
  float a, b;
  if (rel < 288){                       // W1p: k-pairs, row 8 pairs (w1[16], b1)
    int kp = rel >> 5, m = rel & 31;
    a = w1[2*kp*32 + m];
    b = (2*kp+1 < 17) ? w1[(2*kp+1)*32 + m] : b1[m];
  } else if (rel < 832){                // W2p: k-pairs, row 16 = (b2, 0)
    int j = rel - 288, kp = j >> 5, m = j & 31;
    if (kp < 16){ a = w2[2*kp*32 + m]; b = w2[(2*kp+1)*32 + m]; }
    else        { a = b2[m];           b = 0.f; }
  } else if (pair < 3){                 // W3p34: c-pairs, rows 32=b3,33=0
    int j = rel - 832, r = j >> 5, cp = j & 31;
    if      (r < 32){ a = w3[r*64 + 2*cp]; b = w3[r*64 + 2*cp + 1]; }
    else if (r ==32){ a = b3[2*cp];        b = b3[2*cp + 1]; }
    else            { a = 0.f;             b = 0.f; }
  } else {                              // W3p17: m-pairs, mp16 = (b3, 0)
    int j = rel - 832, mp = j / 192, c = j % 192;
    if (mp < 16){ a = w3[2*mp*192 + c]; b = w3[(2*mp+1)*192 + c]; }
    else        { a = b3[c];            b = 0.f; }
  }
  ws[t] = pkh(a, b);
}

// radial MLP: xp in A[0..8], hp (h1 then h2) in A[9..24], A[25]=(1,0) const
__device__ __forceinline__ void mlp(const u32* __restrict__ WL, int pb, u32* __restrict__ A)
{
  float g[32];
  #pragma unroll
  for (int m = 0; m < 32; ++m) g[m] = 0.f;
  #pragma unroll 1
  for (int kp = 0; kp < 9; ++kp){
    v2h x = asvh(A[kp]);
    const u32* __restrict__ r = WL + pb + kp*32;
    #pragma unroll
    for (int m = 0; m < 32; ++m) g[m] = FDOT2(asvh(r[m]), x, g[m]);
  }
  #pragma unroll
  for (int j = 0; j < 16; ++j)
    A[9+j] = pkh(fmaxf(g[2*j], 0.f), fmaxf(g[2*j+1], 0.f));
  float g2[32];
  #pragma unroll
  for (int m = 0; m < 32; ++m) g2[m] = 0.f;
  #pragma unroll 1
  for (int kp = 0; kp < 17; ++kp){                 // kp=16 reads A[25]=(1,0) -> +b2
    v2h x = asvh(A[9+kp]);
    const u32* __restrict__ r = WL + pb + 288 + kp*32;
    #pragma unroll
    for (int m = 0; m < 32; ++m) g2[m] = FDOT2(asvh(r[m]), x, g2[m]);
  }
  #pragma unroll
  for (int j = 0; j < 16; ++j)
    A[9+j] = pkh(fmaxf(g2[2*j], 0.f), fmaxf(g2[2*j+1], 0.f));
}

// layer3, 64 cols (c-paired): acc[o] = sum_rows h_r * (w3row . v), bias via rows 32/33
__device__ __forceinline__ void l3a(const u32* __restrict__ WL, int wb,
                                    const u32* __restrict__ A,
                                    const u32 (&vp)[4], float (&acc)[8])
{
  #pragma unroll
  for (int o = 0; o < 8; ++o) acc[o] = 0.f;
  #pragma unroll 1
  for (int mp = 0; mp < 17; ++mp){
    v2h hp = asvh(A[9+mp]);
    float h0 = (float)hp[0], h1 = (float)hp[1];
    const u32* __restrict__ rA = WL + wb + (2*mp)*32;
    const u32* __restrict__ rB = rA + 32;
    #pragma unroll
    for (int o = 0; o < 8; ++o){
      float tA = 0.f, tB = 0.f;
      #pragma unroll
      for (int j = 0; j < 4; ++j){
        tA = FDOT2(asvh(rA[o*4+j]), asvh(vp[j]), tA);
        tB = FDOT2(asvh(rB[o*4+j]), asvh(vp[j]), tB);
      }
      acc[o] = fmaf(h0, tA, fmaf(h1, tB, acc[o]));
    }
  }
}

__global__ __launch_bounds__(TPB, 3) void edge_kernel(
    const float* __restrict__ feat0, const float* __restrict__ feat1,
    const float* __restrict__ wE,    const float* __restrict__ radial,
    const float* __restrict__ b00,   const float* __restrict__ b01,
    const float* __restrict__ b10,   const float* __restrict__ b11,
    const int* __restrict__ src_idx, const u32* __restrict__ ws,
    float* __restrict__ out)
{
  __shared__ u32 WL[6016];            // class weights (f16 pairs)
  __shared__ u32 AR[TPB * ARENA];
  const int tid = threadIdx.x;
  const int cls = blockIdx.x & 1;
  const int e   = (blockIdx.x >> 1) * TPB + tid;
  u32* A = AR + tid * ARENA;

  { // stage this class's weights (coalesced u32, L2-hot)
    const int gb  = cls ? 3840 : 0;
    const int cnt = cls ? 6016 : 3840;
    for (int j = tid; j < cnt; j += TPB) WL[j] = ws[gb + j];
  }

  // edge features -> f16 pairs in arena
  {
    const float4* wp = (const float4*)(wE + (size_t)e * 16);
    float4 a = wp[0], b = wp[1], c = wp[2], d = wp[3];
    A[0] = pkh(a.x, a.y); A[1] = pkh(a.z, a.w);
    A[2] = pkh(b.x, b.y); A[3] = pkh(b.z, b.w);
    A[4] = pkh(c.x, c.y); A[5] = pkh(c.z, c.w);
    A[6] = pkh(d.x, d.y); A[7] = pkh(d.z, d.w);
    A[8] = pkh(radial[e], 1.0f);      // pairs with (w1[16], b1) row
    A[25] = pkh(1.0f, 0.0f);          // constant (1,0) bias selector
  }
  const int idx = src_idx[e];
  __syncthreads();

  if (cls == 0){
    // ================= class A: pairs (0,0) + (1,0) -> out0 =================
    const float bB = b00[e];
    float B10[3];
    #pragma unroll
    for (int q = 0; q < 3; ++q) B10[q] = b10[(size_t)e*3 + q];
    u32 vp0[4], vp2[4];
    {
      const float4* f0 = (const float4*)(feat0 + (size_t)idx * 8);
      float4 a = f0[0], b = f0[1];
      vp0[0] = pkh(a.x, a.y); vp0[1] = pkh(a.z, a.w);
      vp0[2] = pkh(b.x, b.y); vp0[3] = pkh(b.z, b.w);
      const float4* f1 = (const float4*)(feat1 + (size_t)idx * 24);
      float s1[24];
      #pragma unroll
      for (int j = 0; j < 6; ++j){
        float4 v = f1[j];
        s1[4*j+0]=v.x; s1[4*j+1]=v.y; s1[4*j+2]=v.z; s1[4*j+3]=v.w;
      }
      float Uv[8];
      #pragma unroll
      for (int i = 0; i < 8; ++i)
        Uv[i] = fmaf(B10[0], s1[3*i+0], fmaf(B10[1], s1[3*i+1], B10[2]*s1[3*i+2]));
      #pragma unroll
      for (int j = 0; j < 4; ++j) vp2[j] = pkh(Uv[2*j], Uv[2*j+1]);
    }
    float msg0[8], acc[8];
    mlp(WL, 0, A);
    l3a(WL, 832, A, vp0, acc);
    #pragma unroll
    for (int o = 0; o < 8; ++o) msg0[o] = acc[o] * bB;
    mlp(WL, 1920, A);
    l3a(WL, 1920 + 832, A, vp2, acc);
    #pragma unroll
    for (int o = 0; o < 8; ++o) msg0[o] += acc[o];
    float* o0 = out + (size_t)e * 8;
    ((float4*)o0)[0] = make_float4(msg0[0], msg0[1], msg0[2], msg0[3]);
    ((float4*)o0)[1] = make_float4(msg0[4], msg0[5], msg0[6], msg0[7]);
  } else {
    // ================= class B: pairs (0,1) + (1,1) -> out1 =================
    float B01[3];
    #pragma unroll
    for (int q = 0; q < 3; ++q) B01[q] = b01[(size_t)e*3 + q];
    u32 vp0[4];
    float s1[24];
    {
      const float4* f0 = (const float4*)(feat0 + (size_t)idx * 8);
      float4 a = f0[0], b = f0[1];
      vp0[0] = pkh(a.x, a.y); vp0[1] = pkh(a.z, a.w);
      vp0[2] = pkh(b.x, b.y); vp0[3] = pkh(b.z, b.w);
      const float4* f1 = (const float4*)(feat1 + (size_t)idx * 24);
      #pragma unroll
      for (int j = 0; j < 6; ++j){
        float4 v = f1[j];
        s1[4*j+0]=v.x; s1[4*j+1]=v.y; s1[4*j+2]=v.z; s1[4*j+3]=v.w;
      }
    }
    float t01[8];
    mlp(WL, 0, A);                       // pair (0,1) at class-local 0
    l3a(WL, 832, A, vp0, t01);
    float Bv[27];
    const float* __restrict__ bp = b11 + (size_t)e * 27;
    #pragma unroll
    for (int j = 0; j < 27; ++j) Bv[j] = bp[j];
    mlp(WL, 1920, A);                    // pair (1,1)
    float msg1[24];
    #pragma unroll
    for (int o = 0; o < 8; ++o){         // fully unrolled: msg1/a24 static
      float a24[24];
      #pragma unroll
      for (int c = 0; c < 24; ++c) a24[c] = 0.f;
      #pragma unroll 1
      for (int mp = 0; mp < 17; ++mp){   // mp16 row = (b3,0) with hp=(1,0)
        v2h hp = asvh(A[9+mp]);
        const u32* __restrict__ seg = WL + 2752 + mp*192 + o*24;
        #pragma unroll
        for (int c = 0; c < 24; ++c) a24[c] = FDOT2(asvh(seg[c]), hp, a24[c]);
      }
      float D[9];                        // D[q,f] = sum_i R[o,i,f]*s1[i,q]
      #pragma unroll
      for (int q = 0; q < 3; ++q){
        #pragma unroll
        for (int f = 0; f < 3; ++f){
          float t = 0.f;
          #pragma unroll
          for (int i = 0; i < 8; ++i) t = fmaf(a24[i*3+f], s1[i*3+q], t);
          D[q*3+f] = t;
        }
      }
      #pragma unroll
      for (int p = 0; p < 3; ++p){
        float t = t01[o] * B01[p];
        #pragma unroll
        for (int q = 0; q < 3; ++q){
          #pragma unroll
          for (int f = 0; f < 3; ++f)
            t = fmaf(Bv[p*9 + q*3 + f], D[q*3+f], t);
        }
        msg1[o*3+p] = t;
      }
    }
    float* o1 = out + (size_t)E_TOT * 8 + (size_t)e * 24;
    #pragma unroll
    for (int j = 0; j < 6; ++j)
      ((float4*)o1)[j] = make_float4(msg1[4*j+0], msg1[4*j+1], msg1[4*j+2], msg1[4*j+3]);
  }
}

extern "C" void kernel_launch(void* const* d_in, const int* in_sizes, int n_in,
                              void* d_out, int out_size, void* d_ws, size_t ws_size,
                              hipStream_t stream)
{
  const float* feat0 = (const float*)d_in[0];
  const float* feat1 = (const float*)d_in[1];
  const float* wE    = (const float*)d_in[2];
  const float* rad   = (const float*)d_in[3];
  const float* b00   = (const float*)d_in[4];
  const float* b01   = (const float*)d_in[11];
  const float* b10   = (const float*)d_in[18];
  const float* b11   = (const float*)d_in[25];
  const int* sidx    = (const int*)d_in[32];
  u32* ws            = (u32*)d_ws;

  // ws pair order: (0,0), (1,0), (0,1), (1,1)  -> d_in weight bases 5, 19, 12, 26
  const int base[4] = {5, 19, 12, 26};
  WPtrs S;
  for (int p = 0; p < 4; ++p)
    for (int k = 0; k < 6; ++k)
      S.p[p*6 + k] = (const float*)d_in[base[p] + k];

  prep_kernel<<<39, 256, 0, stream>>>(S, ws);
  edge_kernel<<<NBLK, TPB, 0, stream>>>(feat0, feat1, wE, rad, b00, b01, b10, b11,
                                        sidx, ws, (float*)d_out);
}

// Round 11
// 262.995 us; speedup vs baseline: 3.4434x; 1.0042x over previous
//
#include <hip/hip_runtime.h>

typedef unsigned int u32;
typedef _Float16 v2h __attribute__((ext_vector_type(2)));
typedef __fp16   v2fp __attribute__((ext_vector_type(2)));

#define E_TOT 160000
#define TPB   256
#define NBLK  1250        // (E/256)=625 tiles x 2 classes
#define ARENA 27          // u32/thread: xp[0..8] | hp[9..25] (17) | pad
// ws (u32, f16-pairs): [p(0,0):0..1920) [p(1,0):1920..3840) [p(0,1):3840..5760) [p(1,1):5760..9856)
// per p<3 pair: W1p[9][32]@+0 | W2p[17][32]@+288 | W3p[34 rows][32 cp]@+832   (rows 32=b3,33=0)
// p3 pair:      W1p@+0 | W2p@+288 | W3p[17 mp][192 c]@+832                     (mp16=(b3,0))

#if __has_builtin(__builtin_amdgcn_fdot2)
__device__ __forceinline__ float FDOT2(v2h a, v2h b, float c){
  return __builtin_amdgcn_fdot2(a, b, c, false);
}
#else
__device__ __forceinline__ float FDOT2(v2h a, v2h b, float c){
  return fmaf((float)a[0], (float)b[0], fmaf((float)a[1], (float)b[1], c));
}
#endif

__device__ __forceinline__ u32 pkh(float a, float b){
  union { v2fp h; u32 x; } u;
  u.h = __builtin_amdgcn_cvt_pkrtz(a, b);
  return u.x;
}
__device__ __forceinline__ v2h asvh(u32 x){
  union { u32 x; v2h h; } u; u.x = x; return u.h;
}

struct WPtrs { const float* p[24]; };  // pair order (0,0),(1,0),(0,1),(1,1) x {w1,b1,w2,b2,w3,b3}

__global__ __launch_bounds__(256) void prep_kernel(WPtrs S, u32* __restrict__ ws)
{
  const int t = blockIdx.x * 256 + threadIdx.x;
  if (t >= 9856) return;
  int pair, rel;
  if (t < 5760){ pair = t / 1920; rel = t % 1920; }
  else         { pair = 3;        rel = t - 5760; }
  const float* __restrict__ w1 = S.p[pair*6+0];
  const float* __restrict__ b1 = S.p[pair*6+1];
  const float* __restrict__ w2 = S.p[pair*6+2];
  const float* __restrict__ b2 = S.p[pair*6+3];
  const float* __restrict__ w3 = S.p[pair*6+4];
  const float* __restrict__ b3 = S.p[pair*6+5];
  float a, b;
  if (rel < 288){                       // W1p: k-pairs, row 8 pairs (w1[16], b1)
    int kp = rel >> 5, m = rel & 31;
    a = w1[2*kp*32 + m];
    b = (2*kp+1 < 17) ? w1[(2*kp+1)*32 + m] : b1[m];
  } else if (rel < 832){                // W2p: k-pairs, row 16 = (b2, 0)
    int j = rel - 288, kp = j >> 5, m = j & 31;
    if (kp < 16){ a = w2[2*kp*32 + m]; b = w2[(2*kp+1)*32 + m]; }
    else        { a = b2[m];           b = 0.f; }
  } else if (pair < 3){                 // W3p34: c-pairs, rows 32=b3,33=0
    int j = rel - 832, r = j >> 5, cp = j & 31;
    if      (r < 32){ a = w3[r*64 + 2*cp]; b = w3[r*64 + 2*cp + 1]; }
    else if (r ==32){ a = b3[2*cp];        b = b3[2*cp + 1]; }
    else            { a = 0.f;             b = 0.f; }
  } else {                              // W3p17: m-pairs, mp16 = (b3, 0)
    int j = rel - 832, mp = j / 192, c = j % 192;
    if (mp < 16){ a = w3[2*mp*192 + c]; b = w3[(2*mp+1)*192 + c]; }
    else        { a = b3[c];            b = 0.f; }
  }
  ws[t] = pkh(a, b);
}

// radial MLP: xp in A[0..8], hp (h1 then h2) in A[9..24], A[25]=(1,0) const
__device__ __forceinline__ void mlp(const u32* __restrict__ WL, int pb, u32* __restrict__ A)
{
  float g[32];
  #pragma unroll
  for (int m = 0; m < 32; ++m) g[m] = 0.f;
  #pragma unroll 1
  for (int kp = 0; kp < 9; ++kp){
    v2h x = asvh(A[kp]);
    const uint4* __restrict__ r4 = (const uint4*)(WL + pb + kp*32);
    #pragma unroll
    for (int j = 0; j < 8; ++j){
      uint4 w = r4[j];                               // ds_read_b128
      g[4*j+0] = FDOT2(asvh(w.x), x, g[4*j+0]);
      g[4*j+1] = FDOT2(asvh(w.y), x, g[4*j+1]);
      g[4*j+2] = FDOT2(asvh(w.z), x, g[4*j+2]);
      g[4*j+3] = FDOT2(asvh(w.w), x, g[4*j+3]);
    }
  }
  #pragma unroll
  for (int j = 0; j < 16; ++j)
    A[9+j] = pkh(fmaxf(g[2*j], 0.f), fmaxf(g[2*j+1], 0.f));
  float g2[32];
  #pragma unroll
  for (int m = 0; m < 32; ++m) g2[m] = 0.f;
  #pragma unroll 1
  for (int kp = 0; kp < 17; ++kp){                   // kp=16 reads A[25]=(1,0) -> +b2
    v2h x = asvh(A[9+kp]);
    const uint4* __restrict__ r4 = (const uint4*)(WL + pb + 288 + kp*32);
    #pragma unroll
    for (int j = 0; j < 8; ++j){
      uint4 w = r4[j];
      g2[4*j+0] = FDOT2(asvh(w.x), x, g2[4*j+0]);
      g2[4*j+1] = FDOT2(asvh(w.y), x, g2[4*j+1]);
      g2[4*j+2] = FDOT2(asvh(w.z), x, g2[4*j+2]);
      g2[4*j+3] = FDOT2(asvh(w.w), x, g2[4*j+3]);
    }
  }
  #pragma unroll
  for (int j = 0; j < 16; ++j)
    A[9+j] = pkh(fmaxf(g2[2*j], 0.f), fmaxf(g2[2*j+1], 0.f));
}

// layer3, 64 cols (c-paired): acc[o] = sum_rows h_r * (w3row . v), bias via rows 32/33
__device__ __forceinline__ void l3a(const u32* __restrict__ WL, int wb,
                                    const u32* __restrict__ A,
                                    const u32 (&vp)[4], float (&acc)[8])
{
  #pragma unroll
  for (int o = 0; o < 8; ++o) acc[o] = 0.f;
  #pragma unroll 1
  for (int mp = 0; mp < 17; ++mp){
    v2h hp = asvh(A[9+mp]);
    float h0 = (float)hp[0], h1 = (float)hp[1];
    const uint4* __restrict__ rA = (const uint4*)(WL + wb + (2*mp)*32);
    const uint4* __restrict__ rB = rA + 8;
    #pragma unroll
    for (int o = 0; o < 8; ++o){
      uint4 wa = rA[o];                              // ds_read_b128
      uint4 wb2 = rB[o];
      float tA = 0.f, tB = 0.f;
      tA = FDOT2(asvh(wa.x), asvh(vp[0]), tA);
      tA = FDOT2(asvh(wa.y), asvh(vp[1]), tA);
      tA = FDOT2(asvh(wa.z), asvh(vp[2]), tA);
      tA = FDOT2(asvh(wa.w), asvh(vp[3]), tA);
      tB = FDOT2(asvh(wb2.x), asvh(vp[0]), tB);
      tB = FDOT2(asvh(wb2.y), asvh(vp[1]), tB);
      tB = FDOT2(asvh(wb2.z), asvh(vp[2]), tB);
      tB = FDOT2(asvh(wb2.w), asvh(vp[3]), tB);
      acc[o] = fmaf(h0, tA, fmaf(h1, tB, acc[o]));
    }
  }
}

__global__ __launch_bounds__(TPB, 3) void edge_kernel(
    const float* __restrict__ feat0, const float* __restrict__ feat1,
    const float* __restrict__ wE,    const float* __restrict__ radial,
    const float* __restrict__ b00,   const float* __restrict__ b01,
    const float* __restrict__ b10,   const float* __restrict__ b11,
    const int* __restrict__ src_idx, const u32* __restrict__ ws,
    float* __restrict__ out)
{
  __shared__ __align__(16) u32 WL[6016];   // class weights (f16 pairs)
  __shared__ u32 AR[TPB * ARENA];
  const int tid = threadIdx.x;
  const int cls = blockIdx.x & 1;
  const int e   = (blockIdx.x >> 1) * TPB + tid;
  u32* A = AR + tid * ARENA;

  { // stage this class's weights (coalesced b128, L2-hot)
    const int gb4  = cls ? 960 : 0;        // in uint4 units
    const int cnt4 = cls ? 1504 : 960;
    const uint4* __restrict__ src = (const uint4*)ws;
    uint4* __restrict__ dst = (uint4*)WL;
    for (int j = tid; j < cnt4; j += TPB) dst[j] = src[gb4 + j];
  }

  // edge features -> f16 pairs in arena
  {
    const float4* wp = (const float4*)(wE + (size_t)e * 16);
    float4 a = wp[0], b = wp[1], c = wp[2], d = wp[3];
    A[0] = pkh(a.x, a.y); A[1] = pkh(a.z, a.w);
    A[2] = pkh(b.x, b.y); A[3] = pkh(b.z, b.w);
    A[4] = pkh(c.x, c.y); A[5] = pkh(c.z, c.w);
    A[6] = pkh(d.x, d.y); A[7] = pkh(d.z, d.w);
    A[8] = pkh(radial[e], 1.0f);      // pairs with (w1[16], b1) row
    A[25] = pkh(1.0f, 0.0f);          // constant (1,0) bias selector
  }
  const int idx = src_idx[e];
  __syncthreads();

  if (cls == 0){
    // ================= class A: pairs (0,0) + (1,0) -> out0 =================
    const float bB = b00[e];
    float B10[3];
    #pragma unroll
    for (int q = 0; q < 3; ++q) B10[q] = b10[(size_t)e*3 + q];
    u32 vp0[4], vp2[4];
    {
      const float4* f0 = (const float4*)(feat0 + (size_t)idx * 8);
      float4 a = f0[0], b = f0[1];
      vp0[0] = pkh(a.x, a.y); vp0[1] = pkh(a.z, a.w);
      vp0[2] = pkh(b.x, b.y); vp0[3] = pkh(b.z, b.w);
      const float4* f1 = (const float4*)(feat1 + (size_t)idx * 24);
      float s1[24];
      #pragma unroll
      for (int j = 0; j < 6; ++j){
        float4 v = f1[j];
        s1[4*j+0]=v.x; s1[4*j+1]=v.y; s1[4*j+2]=v.z; s1[4*j+3]=v.w;
      }
      float Uv[8];
      #pragma unroll
      for (int i = 0; i < 8; ++i)
        Uv[i] = fmaf(B10[0], s1[3*i+0], fmaf(B10[1], s1[3*i+1], B10[2]*s1[3*i+2]));
      #pragma unroll
      for (int j = 0; j < 4; ++j) vp2[j] = pkh(Uv[2*j], Uv[2*j+1]);
    }
    float msg0[8], acc[8];
    mlp(WL, 0, A);
    l3a(WL, 832, A, vp0, acc);
    #pragma unroll
    for (int o = 0; o < 8; ++o) msg0[o] = acc[o] * bB;
    mlp(WL, 1920, A);
    l3a(WL, 1920 + 832, A, vp2, acc);
    #pragma unroll
    for (int o = 0; o < 8; ++o) msg0[o] += acc[o];
    float* o0 = out + (size_t)e * 8;
    ((float4*)o0)[0] = make_float4(msg0[0], msg0[1], msg0[2], msg0[3]);
    ((float4*)o0)[1] = make_float4(msg0[4], msg0[5], msg0[6], msg0[7]);
  } else {
    // ================= class B: pairs (0,1) + (1,1) -> out1 =================
    float B01[3];
    #pragma unroll
    for (int q = 0; q < 3; ++q) B01[q] = b01[(size_t)e*3 + q];
    u32 vp0[4];
    float s1[24];
    {
      const float4* f0 = (const float4*)(feat0 + (size_t)idx * 8);
      float4 a = f0[0], b = f0[1];
      vp0[0] = pkh(a.x, a.y); vp0[1] = pkh(a.z, a.w);
      vp0[2] = pkh(b.x, b.y); vp0[3] = pkh(b.z, b.w);
      const float4* f1 = (const float4*)(feat1 + (size_t)idx * 24);
      #pragma unroll
      for (int j = 0; j < 6; ++j){
        float4 v = f1[j];
        s1[4*j+0]=v.x; s1[4*j+1]=v.y; s1[4*j+2]=v.z; s1[4*j+3]=v.w;
      }
    }
    float t01[8];
    mlp(WL, 0, A);                       // pair (0,1) at class-local 0
    l3a(WL, 832, A, vp0, t01);
    float Bv[27];
    const float* __restrict__ bp = b11 + (size_t)e * 27;
    #pragma unroll
    for (int j = 0; j < 27; ++j) Bv[j] = bp[j];
    mlp(WL, 1920, A);                    // pair (1,1)
    float msg1[24];
    #pragma unroll
    for (int o = 0; o < 8; ++o){         // fully unrolled: msg1/a24 static
      float a24[24];
      #pragma unroll
      for (int c = 0; c < 24; ++c) a24[c] = 0.f;
      #pragma unroll 1
      for (int mp = 0; mp < 17; ++mp){   // mp16 row = (b3,0) with hp=(1,0)
        v2h hp = asvh(A[9+mp]);
        const uint4* __restrict__ seg = (const uint4*)(WL + 2752 + mp*192 + o*24);
        #pragma unroll
        for (int j4 = 0; j4 < 6; ++j4){
          uint4 w = seg[j4];             // ds_read_b128
          a24[4*j4+0] = FDOT2(asvh(w.x), hp, a24[4*j4+0]);
          a24[4*j4+1] = FDOT2(asvh(w.y), hp, a24[4*j4+1]);
          a24[4*j4+2] = FDOT2(asvh(w.z), hp, a24[4*j4+2]);
          a24[4*j4+3] = FDOT2(asvh(w.w), hp, a24[4*j4+3]);
        }
      }
      float D[9];                        // D[q,f] = sum_i R[o,i,f]*s1[i,q]
      #pragma unroll
      for (int q = 0; q < 3; ++q){
        #pragma unroll
        for (int f = 0; f < 3; ++f){
          float t = 0.f;
          #pragma unroll
          for (int i = 0; i < 8; ++i) t = fmaf(a24[i*3+f], s1[i*3+q], t);
          D[q*3+f] = t;
        }
      }
      #pragma unroll
      for (int p = 0; p < 3; ++p){
        float t = t01[o] * B01[p];
        #pragma unroll
        for (int q = 0; q < 3; ++q){
          #pragma unroll
          for (int f = 0; f < 3; ++f)
            t = fmaf(Bv[p*9 + q*3 + f], D[q*3+f], t);
        }
        msg1[o*3+p] = t;
      }
    }
    float* o1 = out + (size_t)E_TOT * 8 + (size_t)e * 24;
    #pragma unroll
    for (int j = 0; j < 6; ++j)
      ((float4*)o1)[j] = make_float4(msg1[4*j+0], msg1[4*j+1], msg1[4*j+2], msg1[4*j+3]);
  }
}

extern "C" void kernel_launch(void* const* d_in, const int* in_sizes, int n_in,
                              void* d_out, int out_size, void* d_ws, size_t ws_size,
                              hipStream_t stream)
{
  const float* feat0 = (const float*)d_in[0];
  const float* feat1 = (const float*)d_in[1];
  const float* wE    = (const float*)d_in[2];
  const float* rad   = (const float*)d_in[3];
  const float* b00   = (const float*)d_in[4];
  const float* b01   = (const float*)d_in[11];
  const float* b10   = (const float*)d_in[18];
  const float* b11   = (const float*)d_in[25];
  const int* sidx    = (const int*)d_in[32];
  u32* ws            = (u32*)d_ws;

  // ws pair order: (0,0), (1,0), (0,1), (1,1)  -> d_in weight bases 5, 19, 12, 26
  const int base[4] = {5, 19, 12, 26};
  WPtrs S;
  for (int p = 0; p < 4; ++p)
    for (int k = 0; k < 6; ++k)
      S.p[p*6 + k] = (const float*)d_in[base[p] + k];

  prep_kernel<<<39, 256, 0, stream>>>(S, ws);
  edge_kernel<<<NBLK, TPB, 0, stream>>>(feat0, feat1, wE, rad, b00, b01, b10, b11,
                                        sidx, ws, (float*)d_out);
}